// Round 4
// baseline (13848.686 us; speedup 1.0000x reference)
//
#include <hip/hip_runtime.h>
#include <hip/hip_bf16.h>

using bf16 = __hip_bfloat16;
typedef short v8s __attribute__((ext_vector_type(8)));   // 8 bf16 = 4 VGPRs
typedef float v4f __attribute__((ext_vector_type(4)));   // MFMA C/D frag

__device__ __forceinline__ float sigmoidf_(float x) {
    return 1.0f / (1.0f + __expf(-x));
}
__device__ __forceinline__ float tanhf_(float x) {
    return 1.0f - 2.0f / (__expf(2.0f * x) + 1.0f);
}
__device__ __forceinline__ unsigned short bfbits(float f) {
    bf16 h = __float2bfloat16(f);
    return *reinterpret_cast<unsigned short*>(&h);
}
__device__ __forceinline__ float bf2f(unsigned short u) {
    bf16 h = *reinterpret_cast<bf16*>(&u);
    return __bfloat162float(h);
}

// ---------------- fp32 -> bf16 converter ----------------
__global__ void f2b_kernel(const float* __restrict__ s, bf16* __restrict__ d, int n) {
    int idx = blockIdx.x * blockDim.x + threadIdx.x;
    int stride = gridDim.x * blockDim.x;
    for (int i = idx * 4; i < n; i += stride * 4) {
        float4 v = *reinterpret_cast<const float4*>(s + i);
        ushort4 u;
        u.x = bfbits(v.x); u.y = bfbits(v.y); u.z = bfbits(v.z); u.w = bfbits(v.w);
        *reinterpret_cast<ushort4*>(d + i) = u;
    }
}

// ---------------- init states + barrier counters ----------------
__global__ void init_state_kernel(const float* __restrict__ eh, const float* __restrict__ ec,
                                  float* __restrict__ hf, float* __restrict__ cf,
                                  bf16* __restrict__ hbf, unsigned* __restrict__ counters) {
    int idx = blockIdx.x * blockDim.x + threadIdx.x;
    if (idx < 4) counters[idx * 64] = 0u;   // 4 phase counters, 256B apart
    if (idx >= 2 * 32 * 512) return;
    int l = idx >> 14;          // / 16384
    int rem = idx & 16383;
    hf[idx] = eh[idx];
    cf[idx] = ec[idx];
    hbf[(l * 2 + 0) * 16384 + rem] = __float2bfloat16(eh[idx]);
}

// ---------------- tail: final states -> d_out ----------------
__global__ void tail_kernel(const float* __restrict__ hf, const float* __restrict__ cf,
                            float* __restrict__ out) {
    int idx = blockIdx.x * blockDim.x + threadIdx.x;
    if (idx >= 2 * 32 * 512) return;
    out[1048576 + idx] = hf[idx];
    out[1048576 + 32768 + idx] = cf[idx];
}

// ---------------- bf16 MFMA GEMM: C[M,N] = A[M,K] @ W[N,K]^T (+bias) ----------------
__global__ __launch_bounds__(256) void gemm_bt(
    const bf16* __restrict__ A, const bf16* __restrict__ W,
    const float* __restrict__ bias,
    float* __restrict__ Cf, bf16* __restrict__ Cb,
    int M, int N, int K) {
    __shared__ __align__(16) bf16 As[64][72];
    __shared__ __align__(16) bf16 Bs[64][72];
    const int tid = threadIdx.x;
    const int wave = tid >> 6, lane = tid & 63;
    const int lr = lane & 15, lq = lane >> 4;
    const int m0 = blockIdx.y * 64, n0 = blockIdx.x * 64;

    v4f acc[4];
#pragma unroll
    for (int n = 0; n < 4; ++n) acc[n] = (v4f){0.f, 0.f, 0.f, 0.f};

    for (int k0 = 0; k0 < K; k0 += 64) {
        __syncthreads();
#pragma unroll
        for (int c = tid; c < 512; c += 256) {
            int row = c >> 3, c8 = (c & 7) * 8;
            *reinterpret_cast<v8s*>(&As[row][c8]) =
                *reinterpret_cast<const v8s*>(A + (size_t)(m0 + row) * K + k0 + c8);
            *reinterpret_cast<v8s*>(&Bs[row][c8]) =
                *reinterpret_cast<const v8s*>(W + (size_t)(n0 + row) * K + k0 + c8);
        }
        __syncthreads();
#pragma unroll
        for (int kk = 0; kk < 2; ++kk) {
            v8s a = *reinterpret_cast<const v8s*>(&As[wave * 16 + lr][kk * 32 + lq * 8]);
#pragma unroll
            for (int n = 0; n < 4; ++n) {
                v8s b = *reinterpret_cast<const v8s*>(&Bs[n * 16 + lr][kk * 32 + lq * 8]);
                acc[n] = __builtin_amdgcn_mfma_f32_16x16x32_bf16(a, b, acc[n], 0, 0, 0);
            }
        }
    }
#pragma unroll
    for (int n = 0; n < 4; ++n) {
        int col = n0 + n * 16 + lr;
        float bv = bias ? bias[col] : 0.0f;
#pragma unroll
        for (int r = 0; r < 4; ++r) {
            int row = m0 + wave * 16 + lq * 4 + r;
            float v = acc[n][r] + bv;
            if (Cf) Cf[(size_t)row * N + col] = v;
            if (Cb) Cb[(size_t)row * N + col] = __float2bfloat16(v);
        }
    }
}

// ---------------- persistent LSTM layer + clock warmers ----------------
// grid = 256 WGs x 256 thr (1/CU). WGs 0..31: real work (WG j owns hidden cols
// [j*16, j*16+16), wave w = gate w). WGs 32..255: dependent-FMA clock warmers
// that spin until this phase's barrier counter hits 32*T (anti-DVFS).
// h ping-pong: instruction-level device-coherent (relaxed agent atomics), no fences.
__global__ __launch_bounds__(256) void lstm_layer_persist(
    int T,
    bf16* __restrict__ h0, bf16* __restrict__ h1,   // ping-pong [32*512] bf16
    float* __restrict__ hf, float* __restrict__ cf,  // [32*512] fp32 state
    const bf16* __restrict__ Whh,                    // [2048][512]
    const float* __restrict__ xpf,                   // fp32 xproj [(b*T+t)*2048] or null
    const bf16* __restrict__ xpb,                    // bf16 xproj or null
    const float* __restrict__ bih, const float* __restrict__ bhh,
    bf16* __restrict__ seq, long seq_stride_b,       // optional bf16 h seq out
    float* __restrict__ outf, long out_stride_b,     // optional fp32 h seq out
    unsigned* __restrict__ bar)
{
    const int tid = threadIdx.x;

    // ---------- clock warmers ----------
    if (blockIdx.x >= 32) {
        const unsigned target = 32u * (unsigned)T;
        float a0 = 1.0f + (float)tid * 1e-6f, a1 = 1.1f, a2 = 1.2f, a3 = 1.3f;
        while (__hip_atomic_load(bar, __ATOMIC_RELAXED, __HIP_MEMORY_SCOPE_AGENT) < target) {
#pragma unroll
            for (int i = 0; i < 256; ++i) {
                a0 = __builtin_fmaf(a0, 0.99991f, 1e-7f);
                a1 = __builtin_fmaf(a1, 0.99992f, 1e-7f);
                a2 = __builtin_fmaf(a2, 0.99993f, 1e-7f);
                a3 = __builtin_fmaf(a3, 0.99994f, 1e-7f);
            }
            asm volatile("" : "+v"(a0), "+v"(a1), "+v"(a2), "+v"(a3));
        }
        return;
    }

    // ---------- real work ----------
    __shared__ float gs[4][32][16];
    __shared__ float bias_s[4][16];
    const int wave = tid >> 6, lane = tid & 63;
    const int lr = lane & 15, lq = lane >> 4;
    const int hc0 = blockIdx.x * 16;

    if (tid < 64) {
        int g = tid >> 4, col = tid & 15;
        bias_s[g][col] = bih[g * 512 + hc0 + col] + bhh[g * 512 + hc0 + col];
    }

    // pointwise ownership: batch pb, cols pc & pc+1 (c register-resident)
    const int pb = tid >> 3;
    const int pc = (tid & 7) * 2;
    const int pgc = hc0 + pc;

    float c0, c1;
    {
        size_t sidx = (size_t)pb * 512 + pgc;
        c0 = cf[sidx]; c1 = cf[sidx + 1];
    }

    // Whh slice (gate `wave`, cols hc0+lr) pinned into registers (AGPR-eligible).
    v8s breg[16];
    {
        const bf16* wrow = Whh + (size_t)(wave * 512 + hc0 + lr) * 512 + lq * 8;
#pragma unroll
        for (int kk = 0; kk < 16; ++kk)
            breg[kk] = *reinterpret_cast<const v8s*>(wrow + kk * 32);
    }
    asm volatile("" : "+v"(breg[0]), "+v"(breg[1]), "+v"(breg[2]), "+v"(breg[3]),
                      "+v"(breg[4]), "+v"(breg[5]), "+v"(breg[6]), "+v"(breg[7]),
                      "+v"(breg[8]), "+v"(breg[9]), "+v"(breg[10]), "+v"(breg[11]),
                      "+v"(breg[12]), "+v"(breg[13]), "+v"(breg[14]), "+v"(breg[15]));
    __syncthreads();

    // xp prefetch helper: loads the 8 gate inputs for (pb, pgc..pgc+1) at step t
    auto load_xp = [&](int t, float* xv) {
        if (xpf) {
            const float* xp = xpf + ((size_t)pb * T + t) * 2048;
            float2 a = *reinterpret_cast<const float2*>(xp + pgc);
            float2 b = *reinterpret_cast<const float2*>(xp + 512 + pgc);
            float2 c = *reinterpret_cast<const float2*>(xp + 1024 + pgc);
            float2 d = *reinterpret_cast<const float2*>(xp + 1536 + pgc);
            xv[0] = a.x; xv[1] = a.y; xv[2] = b.x; xv[3] = b.y;
            xv[4] = c.x; xv[5] = c.y; xv[6] = d.x; xv[7] = d.y;
        } else {
            const bf16* xp = xpb + ((size_t)pb * T + t) * 2048;
            unsigned a = *reinterpret_cast<const unsigned*>(xp + pgc);
            unsigned b = *reinterpret_cast<const unsigned*>(xp + 512 + pgc);
            unsigned c = *reinterpret_cast<const unsigned*>(xp + 1024 + pgc);
            unsigned d = *reinterpret_cast<const unsigned*>(xp + 1536 + pgc);
            xv[0] = bf2f(a & 0xffff); xv[1] = bf2f(a >> 16);
            xv[2] = bf2f(b & 0xffff); xv[3] = bf2f(b >> 16);
            xv[4] = bf2f(c & 0xffff); xv[5] = bf2f(c >> 16);
            xv[6] = bf2f(d & 0xffff); xv[7] = bf2f(d >> 16);
        }
    };

    float xcur[8];
    load_xp(0, xcur);

    for (int t = 0; t < T; ++t) {
        const bf16* hin = (t & 1) ? h1 : h0;
        bf16* hout      = (t & 1) ? h0 : h1;

        // ---- hidden GEMM: A loads are device-coherent 8B relaxed atomics ----
        unsigned long long* hbase = (unsigned long long*)hin;
        v4f acc0 = (v4f){0.f, 0.f, 0.f, 0.f};
        v4f acc1 = (v4f){0.f, 0.f, 0.f, 0.f};
#pragma unroll 4
        for (int kk = 0; kk < 16; ++kk) {
            union { unsigned long long u[2]; v8s v; } a0u, a1u;
            unsigned long long* p0 = hbase + (size_t)lr * 128 + lq * 2 + kk * 8;
            a0u.u[0] = __hip_atomic_load(p0,     __ATOMIC_RELAXED, __HIP_MEMORY_SCOPE_AGENT);
            a0u.u[1] = __hip_atomic_load(p0 + 1, __ATOMIC_RELAXED, __HIP_MEMORY_SCOPE_AGENT);
            unsigned long long* p1 = p0 + 2048;  // batches 16..31
            a1u.u[0] = __hip_atomic_load(p1,     __ATOMIC_RELAXED, __HIP_MEMORY_SCOPE_AGENT);
            a1u.u[1] = __hip_atomic_load(p1 + 1, __ATOMIC_RELAXED, __HIP_MEMORY_SCOPE_AGENT);
            acc0 = __builtin_amdgcn_mfma_f32_16x16x32_bf16(a0u.v, breg[kk], acc0, 0, 0, 0);
            acc1 = __builtin_amdgcn_mfma_f32_16x16x32_bf16(a1u.v, breg[kk], acc1, 0, 0, 0);
        }
#pragma unroll
        for (int r = 0; r < 4; ++r) {
            gs[wave][lq * 4 + r][lr]      = acc0[r];
            gs[wave][16 + lq * 4 + r][lr] = acc1[r];
        }
        __syncthreads();

        // ---- pointwise: this thread's (pb, pc..pc+1) ----
        float gi0 = gs[0][pb][pc]     + xcur[0] + bias_s[0][pc];
        float gi1 = gs[0][pb][pc + 1] + xcur[1] + bias_s[0][pc + 1];
        float gf0 = gs[1][pb][pc]     + xcur[2] + bias_s[1][pc];
        float gf1 = gs[1][pb][pc + 1] + xcur[3] + bias_s[1][pc + 1];
        float gg0 = gs[2][pb][pc]     + xcur[4] + bias_s[2][pc];
        float gg1 = gs[2][pb][pc + 1] + xcur[5] + bias_s[2][pc + 1];
        float go0 = gs[3][pb][pc]     + xcur[6] + bias_s[3][pc];
        float go1 = gs[3][pb][pc + 1] + xcur[7] + bias_s[3][pc + 1];

        c0 = sigmoidf_(gf0) * c0 + sigmoidf_(gi0) * tanhf_(gg0);
        c1 = sigmoidf_(gf1) * c1 + sigmoidf_(gi1) * tanhf_(gg1);
        float h0v = sigmoidf_(go0) * tanhf_(c0);
        float h1v = sigmoidf_(go1) * tanhf_(c1);

        unsigned hp = (unsigned)bfbits(h0v) | ((unsigned)bfbits(h1v) << 16);
        __hip_atomic_store(reinterpret_cast<unsigned*>(hout + (size_t)pb * 512 + pgc),
                           hp, __ATOMIC_RELAXED, __HIP_MEMORY_SCOPE_AGENT);
        if (seq)
            *reinterpret_cast<unsigned*>(seq + (size_t)pb * seq_stride_b + (size_t)t * 512 + pgc) = hp;
        if (outf) {
            float2 hv; hv.x = h0v; hv.y = h1v;
            *reinterpret_cast<float2*>(outf + (size_t)pb * out_stride_b + (size_t)t * 512 + pgc) = hv;
        }
        if (t == T - 1) {
            size_t sidx = (size_t)pb * 512 + pgc;
            hf[sidx] = h0v; hf[sidx + 1] = h1v;
            cf[sidx] = c0;  cf[sidx + 1] = c1;
        }

        // ---- prefetch xp for t+1 BEFORE the barrier: its latency drains in the
        // pre-barrier vmcnt(0), overlapped with other WGs' arrival skew ----
        if (t + 1 < T) load_xp(t + 1, xcur);

        // ---- fence-free grid barrier (busy poll; warmers keep clocks up) ----
        __syncthreads();   // drains vmcnt(0): h stores agent-visible before arrive
        if (tid == 0) {
            __hip_atomic_fetch_add(bar, 1u, __ATOMIC_RELAXED, __HIP_MEMORY_SCOPE_AGENT);
            unsigned target = 32u * (unsigned)(t + 1);
            while (__hip_atomic_load(bar, __ATOMIC_RELAXED, __HIP_MEMORY_SCOPE_AGENT) < target) {}
        }
        __syncthreads();
    }
}

// ---------------- host orchestration ----------------
extern "C" void kernel_launch(void* const* d_in, const int* in_sizes, int n_in,
                              void* d_out, int out_size, void* d_ws, size_t ws_size,
                              hipStream_t stream) {
    constexpr int B = 32, S = 512, F = 64, I = 512, H = 512, G = 2048;

    const float* x    = (const float*)d_in[0];
    const float* fut  = (const float*)d_in[1];
    const float* eh   = (const float*)d_in[2];
    const float* ec   = (const float*)d_in[3];
    const float* fc_w = (const float*)d_in[4];
    const float* fc_b = (const float*)d_in[5];
    const float* ewih = (const float*)d_in[6];
    const float* ewhh = (const float*)d_in[7];
    const float* ebih = (const float*)d_in[8];
    const float* ebhh = (const float*)d_in[9];
    const float* dwih = (const float*)d_in[10];
    const float* dwhh = (const float*)d_in[11];
    const float* dbih = (const float*)d_in[12];
    const float* dbhh = (const float*)d_in[13];
    float* out = (float*)d_out;

    char* ws = (char*)d_ws;
    size_t off = 0;
    auto alloc = [&](size_t bytes) -> char* {
        char* p = ws + off;
        off += (bytes + 255) & ~(size_t)255;
        return p;
    };

    bf16* x_bf    = (bf16*)alloc((size_t)B * S * I * 2);
    bf16* fut_bf  = (bf16*)alloc((size_t)B * F * I * 2);
    bf16* fcw_bf  = (bf16*)alloc((size_t)H * I * 2);
    bf16* ewih_bf = (bf16*)alloc((size_t)2 * G * H * 2);
    bf16* ewhh_bf = (bf16*)alloc((size_t)2 * G * H * 2);
    bf16* dwih_bf = (bf16*)alloc((size_t)2 * G * H * 2);
    bf16* dwhh_bf = (bf16*)alloc((size_t)2 * G * H * 2);
    bf16* xt_bf   = (bf16*)alloc((size_t)B * S * H * 2);
    bf16* h0seq   = (bf16*)alloc((size_t)B * S * H * 2);
    bf16* hD0seq  = (bf16*)alloc((size_t)B * F * H * 2);
    bf16* hbf     = (bf16*)alloc((size_t)2 * 2 * B * H * 2);  // [L][slot][B*H]
    float* hf     = (float*)alloc((size_t)2 * B * H * 4);
    float* cf     = (float*)alloc((size_t)2 * B * H * 4);
    unsigned* bar = (unsigned*)alloc(4 * 64 * sizeof(unsigned)); // 4 counters, 256B apart

    size_t xp32_bytes = (size_t)B * S * G * 4;
    bool xp32 = (ws_size - off) >= xp32_bytes + 4096;
    float* Xf = nullptr; bf16* Xb = nullptr;
    if (xp32) Xf = (float*)alloc(xp32_bytes);
    else      Xb = (bf16*)alloc((size_t)B * S * G * 2);

    auto cvt = [&](const float* s, bf16* d, int n) {
        int blocks = (n / 4 + 255) / 256;
        if (blocks > 4096) blocks = 4096;
        f2b_kernel<<<blocks, 256, 0, stream>>>(s, d, n);
    };
    cvt(x, x_bf, B * S * I);
    cvt(fut, fut_bf, B * F * I);
    cvt(fc_w, fcw_bf, H * I);
    cvt(ewih, ewih_bf, 2 * G * H);
    cvt(ewhh, ewhh_bf, 2 * G * H);
    cvt(dwih, dwih_bf, 2 * G * H);
    cvt(dwhh, dwhh_bf, 2 * G * H);

    init_state_kernel<<<128, 256, 0, stream>>>(eh, ec, hf, cf, hbf, bar);

    auto gemm = [&](const bf16* A, const bf16* W, const float* bias,
                    float* Cf_, bf16* Cb_, int M, int N, int K) {
        gemm_bt<<<dim3(N / 64, M / 64), 256, 0, stream>>>(A, W, bias, Cf_, Cb_, M, N, K);
    };

    // FC: xt = bf16(x @ fc_w^T + fc_b)
    gemm(x_bf, fcw_bf, fc_b, nullptr, xt_bf, B * S, H, I);

    auto run_phase = [&](const bf16* Whh_l, const float* bih_l, const float* bhh_l,
                         int layer, int T, int phase,
                         bf16* seq_base, long seq_stride,
                         float* out_base, long out_stride) {
        lstm_layer_persist<<<256, 256, 0, stream>>>(
            T,
            hbf + (size_t)(layer * 2 + 0) * (B * H),
            hbf + (size_t)(layer * 2 + 1) * (B * H),
            hf + (size_t)layer * B * H, cf + (size_t)layer * B * H,
            Whh_l, Xf, Xb, bih_l, bhh_l,
            seq_base, seq_stride, out_base, out_stride,
            bar + phase * 64);
    };

    // ---- Encoder layer 0 ----
    gemm(xt_bf, ewih_bf, nullptr, Xf, Xb, B * S, G, H);
    run_phase(ewhh_bf, ebih, ebhh, 0, S, 0, h0seq, (long)S * H, nullptr, 0);

    // ---- Encoder layer 1 ---- (sequence discarded; only final state matters)
    gemm(h0seq, ewih_bf + (size_t)G * H, nullptr, Xf, Xb, B * S, G, H);
    run_phase(ewhh_bf + (size_t)G * H, ebih + G, ebhh + G, 1, S, 1, nullptr, 0, nullptr, 0);

    // ---- Decoder layer 0 ---- (initial state = encoder finals; S even -> h in slot 0)
    gemm(fut_bf, dwih_bf, nullptr, Xf, Xb, B * F, G, H);
    run_phase(dwhh_bf, dbih, dbhh, 0, F, 2, hD0seq, (long)F * H, nullptr, 0);

    // ---- Decoder layer 1 ---- writes dec_out directly
    gemm(hD0seq, dwih_bf + (size_t)G * H, nullptr, Xf, Xb, B * F, G, H);
    run_phase(dwhh_bf + (size_t)G * H, dbih + G, dbhh + G, 1, F, 3, nullptr, 0, out, (long)F * H);

    // ---- Final decoder states ----
    tail_kernel<<<128, 256, 0, stream>>>(hf, cf, out);
}

// Round 5
// 4395.214 us; speedup vs baseline: 3.1509x; 3.1509x over previous
//
#include <hip/hip_runtime.h>
#include <hip/hip_bf16.h>

using bf16 = __hip_bfloat16;
typedef short v8s __attribute__((ext_vector_type(8)));   // 8 bf16 = 4 VGPRs
typedef float v4f __attribute__((ext_vector_type(4)));   // MFMA C/D frag

__device__ __forceinline__ float sigmoidf_(float x) {
    return 1.0f / (1.0f + __expf(-x));
}
__device__ __forceinline__ float tanhf_(float x) {
    return 1.0f - 2.0f / (__expf(2.0f * x) + 1.0f);
}
__device__ __forceinline__ unsigned short bfbits(float f) {
    bf16 h = __float2bfloat16(f);
    return *reinterpret_cast<unsigned short*>(&h);
}
__device__ __forceinline__ float bf2f(unsigned short u) {
    bf16 h = *reinterpret_cast<bf16*>(&u);
    return __bfloat162float(h);
}

// 16B load that bypasses L1+L2 (reads the coherent point). Issue-only; caller
// must s_waitcnt before use.
__device__ __forceinline__ v8s load_b128_coherent(const bf16* p) {
    v8s r;
    asm volatile("global_load_dwordx4 %0, %1, off sc0 sc1"
                 : "=v"(r) : "v"(p) : "memory");
    return r;
}

// ---------------- fp32 -> bf16 converter ----------------
__global__ void f2b_kernel(const float* __restrict__ s, bf16* __restrict__ d, int n) {
    int idx = blockIdx.x * blockDim.x + threadIdx.x;
    int stride = gridDim.x * blockDim.x;
    for (int i = idx * 4; i < n; i += stride * 4) {
        float4 v = *reinterpret_cast<const float4*>(s + i);
        ushort4 u;
        u.x = bfbits(v.x); u.y = bfbits(v.y); u.z = bfbits(v.z); u.w = bfbits(v.w);
        *reinterpret_cast<ushort4*>(d + i) = u;
    }
}

// ---------------- init states + barrier counters ----------------
__global__ void init_state_kernel(const float* __restrict__ eh, const float* __restrict__ ec,
                                  float* __restrict__ hf, float* __restrict__ cf,
                                  bf16* __restrict__ hbf, unsigned* __restrict__ counters) {
    int idx = blockIdx.x * blockDim.x + threadIdx.x;
    if (idx < 4) counters[idx * 64] = 0u;   // 4 phase counters, 256B apart
    if (idx >= 2 * 32 * 512) return;
    int l = idx >> 14;          // / 16384
    int rem = idx & 16383;
    hf[idx] = eh[idx];
    cf[idx] = ec[idx];
    hbf[(l * 2 + 0) * 16384 + rem] = __float2bfloat16(eh[idx]);
}

// ---------------- tail: final states -> d_out ----------------
__global__ void tail_kernel(const float* __restrict__ hf, const float* __restrict__ cf,
                            float* __restrict__ out) {
    int idx = blockIdx.x * blockDim.x + threadIdx.x;
    if (idx >= 2 * 32 * 512) return;
    out[1048576 + idx] = hf[idx];
    out[1048576 + 32768 + idx] = cf[idx];
}

// ---------------- bf16 MFMA GEMM: C[M,N] = A[M,K] @ W[N,K]^T (+bias) ----------------
__global__ __launch_bounds__(256) void gemm_bt(
    const bf16* __restrict__ A, const bf16* __restrict__ W,
    const float* __restrict__ bias,
    float* __restrict__ Cf, bf16* __restrict__ Cb,
    int M, int N, int K) {
    __shared__ __align__(16) bf16 As[64][72];
    __shared__ __align__(16) bf16 Bs[64][72];
    const int tid = threadIdx.x;
    const int wave = tid >> 6, lane = tid & 63;
    const int lr = lane & 15, lq = lane >> 4;
    const int m0 = blockIdx.y * 64, n0 = blockIdx.x * 64;

    v4f acc[4];
#pragma unroll
    for (int n = 0; n < 4; ++n) acc[n] = (v4f){0.f, 0.f, 0.f, 0.f};

    for (int k0 = 0; k0 < K; k0 += 64) {
        __syncthreads();
#pragma unroll
        for (int c = tid; c < 512; c += 256) {
            int row = c >> 3, c8 = (c & 7) * 8;
            *reinterpret_cast<v8s*>(&As[row][c8]) =
                *reinterpret_cast<const v8s*>(A + (size_t)(m0 + row) * K + k0 + c8);
            *reinterpret_cast<v8s*>(&Bs[row][c8]) =
                *reinterpret_cast<const v8s*>(W + (size_t)(n0 + row) * K + k0 + c8);
        }
        __syncthreads();
#pragma unroll
        for (int kk = 0; kk < 2; ++kk) {
            v8s a = *reinterpret_cast<const v8s*>(&As[wave * 16 + lr][kk * 32 + lq * 8]);
#pragma unroll
            for (int n = 0; n < 4; ++n) {
                v8s b = *reinterpret_cast<const v8s*>(&Bs[n * 16 + lr][kk * 32 + lq * 8]);
                acc[n] = __builtin_amdgcn_mfma_f32_16x16x32_bf16(a, b, acc[n], 0, 0, 0);
            }
        }
    }
#pragma unroll
    for (int n = 0; n < 4; ++n) {
        int col = n0 + n * 16 + lr;
        float bv = bias ? bias[col] : 0.0f;
#pragma unroll
        for (int r = 0; r < 4; ++r) {
            int row = m0 + wave * 16 + lq * 4 + r;
            float v = acc[n][r] + bv;
            if (Cf) Cf[(size_t)row * N + col] = v;
            if (Cb) Cb[(size_t)row * N + col] = __float2bfloat16(v);
        }
    }
}

// ---------------- persistent LSTM layer ----------------
// 32 WGs x 256 thr, co-resident. WG j owns hidden cols [j*16,j*16+16), wave w
// = gate w (i,f,g,o). Per step: stage full h into LDS via 8 pipelined coherent
// b128 loads/thread (ONE MALL latency), MFMA from LDS, pointwise, coherent h
// store, fence-free central-counter barrier.
__global__ __launch_bounds__(256, 1) void lstm_layer_persist(
    int T,
    bf16* __restrict__ h0, bf16* __restrict__ h1,   // ping-pong [32*512] bf16
    float* __restrict__ hf, float* __restrict__ cf,  // [32*512] fp32 state
    const bf16* __restrict__ Whh,                    // [2048][512]
    const float* __restrict__ xpf,                   // fp32 xproj [(b*T+t)*2048] or null
    const bf16* __restrict__ xpb,                    // bf16 xproj or null
    const float* __restrict__ bih, const float* __restrict__ bhh,
    bf16* __restrict__ seq, long seq_stride_b,       // optional bf16 h seq out
    float* __restrict__ outf, long out_stride_b,     // optional fp32 h seq out
    unsigned* __restrict__ bar)
{
    __shared__ __align__(16) bf16 hs[32][520];   // +8 pad: kills 16-way ds_read conflict
    __shared__ float gs[4][32][16];
    __shared__ float bias_s[4][16];
    const int tid = threadIdx.x;
    const int wave = tid >> 6, lane = tid & 63;
    const int lr = lane & 15, lq = lane >> 4;
    const int hc0 = blockIdx.x * 16;

    if (tid < 64) {
        int g = tid >> 4, col = tid & 15;
        bias_s[g][col] = bih[g * 512 + hc0 + col] + bhh[g * 512 + hc0 + col];
    }

    // pointwise ownership: batch pb, cols pc & pc+1 (c register-resident)
    const int pb = tid >> 3;
    const int pc = (tid & 7) * 2;
    const int pgc = hc0 + pc;

    float c0, c1;
    {
        size_t sidx = (size_t)pb * 512 + pgc;
        c0 = cf[sidx]; c1 = cf[sidx + 1];
    }

    // Whh slice (gate `wave`, cols hc0+lr): 16 x v8s = 64 VGPRs, kept resident.
    v8s breg[16];
    {
        const bf16* wrow = Whh + (size_t)(wave * 512 + hc0 + lr) * 512 + lq * 8;
#pragma unroll
        for (int kk = 0; kk < 16; ++kk)
            breg[kk] = *reinterpret_cast<const v8s*>(wrow + kk * 32);
    }
    __syncthreads();

    // staging geometry: thread tid covers elements tid*8 + i*2048, i=0..7
    const int st_row = tid >> 6;          // base row (i adds 4 per step)
    const int st_col = (tid * 8) & 511;

    auto load_xp = [&](int t, float* xv) {
        if (xpf) {
            const float* xp = xpf + ((size_t)pb * T + t) * 2048;
            float2 a = *reinterpret_cast<const float2*>(xp + pgc);
            float2 b = *reinterpret_cast<const float2*>(xp + 512 + pgc);
            float2 c = *reinterpret_cast<const float2*>(xp + 1024 + pgc);
            float2 d = *reinterpret_cast<const float2*>(xp + 1536 + pgc);
            xv[0] = a.x; xv[1] = a.y; xv[2] = b.x; xv[3] = b.y;
            xv[4] = c.x; xv[5] = c.y; xv[6] = d.x; xv[7] = d.y;
        } else {
            const bf16* xp = xpb + ((size_t)pb * T + t) * 2048;
            unsigned a = *reinterpret_cast<const unsigned*>(xp + pgc);
            unsigned b = *reinterpret_cast<const unsigned*>(xp + 512 + pgc);
            unsigned c = *reinterpret_cast<const unsigned*>(xp + 1024 + pgc);
            unsigned d = *reinterpret_cast<const unsigned*>(xp + 1536 + pgc);
            xv[0] = bf2f(a & 0xffff); xv[1] = bf2f(a >> 16);
            xv[2] = bf2f(b & 0xffff); xv[3] = bf2f(b >> 16);
            xv[4] = bf2f(c & 0xffff); xv[5] = bf2f(c >> 16);
            xv[6] = bf2f(d & 0xffff); xv[7] = bf2f(d >> 16);
        }
    };

    float xcur[8];
    load_xp(0, xcur);

    for (int t = 0; t < T; ++t) {
        const bf16* hin = (t & 1) ? h1 : h0;
        bf16* hout      = (t & 1) ? h0 : h1;

        // ---- stage h -> LDS: 8 independent coherent b128 loads, ONE wait ----
        {
            const bf16* src = hin + tid * 8;
            v8s r0 = load_b128_coherent(src);
            v8s r1 = load_b128_coherent(src + 1 * 2048);
            v8s r2 = load_b128_coherent(src + 2 * 2048);
            v8s r3 = load_b128_coherent(src + 3 * 2048);
            v8s r4 = load_b128_coherent(src + 4 * 2048);
            v8s r5 = load_b128_coherent(src + 5 * 2048);
            v8s r6 = load_b128_coherent(src + 6 * 2048);
            v8s r7 = load_b128_coherent(src + 7 * 2048);
            asm volatile("s_waitcnt vmcnt(0)"
                         : "+v"(r0), "+v"(r1), "+v"(r2), "+v"(r3),
                           "+v"(r4), "+v"(r5), "+v"(r6), "+v"(r7));
            *reinterpret_cast<v8s*>(&hs[st_row +  0][st_col]) = r0;
            *reinterpret_cast<v8s*>(&hs[st_row +  4][st_col]) = r1;
            *reinterpret_cast<v8s*>(&hs[st_row +  8][st_col]) = r2;
            *reinterpret_cast<v8s*>(&hs[st_row + 12][st_col]) = r3;
            *reinterpret_cast<v8s*>(&hs[st_row + 16][st_col]) = r4;
            *reinterpret_cast<v8s*>(&hs[st_row + 20][st_col]) = r5;
            *reinterpret_cast<v8s*>(&hs[st_row + 24][st_col]) = r6;
            *reinterpret_cast<v8s*>(&hs[st_row + 28][st_col]) = r7;
        }
        __syncthreads();

        // ---- hidden GEMM from LDS ----
        v4f acc0 = (v4f){0.f, 0.f, 0.f, 0.f};
        v4f acc1 = (v4f){0.f, 0.f, 0.f, 0.f};
#pragma unroll
        for (int kk = 0; kk < 16; ++kk) {
            v8s a0 = *reinterpret_cast<const v8s*>(&hs[lr][lq * 8 + kk * 32]);
            v8s a1 = *reinterpret_cast<const v8s*>(&hs[16 + lr][lq * 8 + kk * 32]);
            acc0 = __builtin_amdgcn_mfma_f32_16x16x32_bf16(a0, breg[kk], acc0, 0, 0, 0);
            acc1 = __builtin_amdgcn_mfma_f32_16x16x32_bf16(a1, breg[kk], acc1, 0, 0, 0);
        }
#pragma unroll
        for (int r = 0; r < 4; ++r) {
            gs[wave][lq * 4 + r][lr]      = acc0[r];
            gs[wave][16 + lq * 4 + r][lr] = acc1[r];
        }
        __syncthreads();

        // ---- pointwise: this thread's (pb, pc..pc+1) ----
        float gi0 = gs[0][pb][pc]     + xcur[0] + bias_s[0][pc];
        float gi1 = gs[0][pb][pc + 1] + xcur[1] + bias_s[0][pc + 1];
        float gf0 = gs[1][pb][pc]     + xcur[2] + bias_s[1][pc];
        float gf1 = gs[1][pb][pc + 1] + xcur[3] + bias_s[1][pc + 1];
        float gg0 = gs[2][pb][pc]     + xcur[4] + bias_s[2][pc];
        float gg1 = gs[2][pb][pc + 1] + xcur[5] + bias_s[2][pc + 1];
        float go0 = gs[3][pb][pc]     + xcur[6] + bias_s[3][pc];
        float go1 = gs[3][pb][pc + 1] + xcur[7] + bias_s[3][pc + 1];

        c0 = sigmoidf_(gf0) * c0 + sigmoidf_(gi0) * tanhf_(gg0);
        c1 = sigmoidf_(gf1) * c1 + sigmoidf_(gi1) * tanhf_(gg1);
        float h0v = sigmoidf_(go0) * tanhf_(c0);
        float h1v = sigmoidf_(go1) * tanhf_(c1);

        unsigned hp = (unsigned)bfbits(h0v) | ((unsigned)bfbits(h1v) << 16);
        __hip_atomic_store(reinterpret_cast<unsigned*>(hout + (size_t)pb * 512 + pgc),
                           hp, __ATOMIC_RELAXED, __HIP_MEMORY_SCOPE_AGENT);
        if (seq)
            *reinterpret_cast<unsigned*>(seq + (size_t)pb * seq_stride_b + (size_t)t * 512 + pgc) = hp;
        if (outf) {
            float2 hv; hv.x = h0v; hv.y = h1v;
            *reinterpret_cast<float2*>(outf + (size_t)pb * out_stride_b + (size_t)t * 512 + pgc) = hv;
        }
        if (t == T - 1) {
            size_t sidx = (size_t)pb * 512 + pgc;
            hf[sidx] = h0v; hf[sidx + 1] = h1v;
            cf[sidx] = c0;  cf[sidx + 1] = c1;
        }

        // prefetch xp(t+1): latency drains inside the barrier's vmcnt(0)
        if (t + 1 < T) load_xp(t + 1, xcur);

        // ---- fence-free grid barrier ----
        __syncthreads();   // drains vmcnt(0): h stores agent-visible before arrive
        if (tid == 0) {
            __hip_atomic_fetch_add(bar, 1u, __ATOMIC_RELAXED, __HIP_MEMORY_SCOPE_AGENT);
            unsigned target = 32u * (unsigned)(t + 1);
            while (__hip_atomic_load(bar, __ATOMIC_RELAXED, __HIP_MEMORY_SCOPE_AGENT) < target) {}
        }
        __syncthreads();
    }
}

// ---------------- host orchestration ----------------
extern "C" void kernel_launch(void* const* d_in, const int* in_sizes, int n_in,
                              void* d_out, int out_size, void* d_ws, size_t ws_size,
                              hipStream_t stream) {
    constexpr int B = 32, S = 512, F = 64, I = 512, H = 512, G = 2048;

    const float* x    = (const float*)d_in[0];
    const float* fut  = (const float*)d_in[1];
    const float* eh   = (const float*)d_in[2];
    const float* ec   = (const float*)d_in[3];
    const float* fc_w = (const float*)d_in[4];
    const float* fc_b = (const float*)d_in[5];
    const float* ewih = (const float*)d_in[6];
    const float* ewhh = (const float*)d_in[7];
    const float* ebih = (const float*)d_in[8];
    const float* ebhh = (const float*)d_in[9];
    const float* dwih = (const float*)d_in[10];
    const float* dwhh = (const float*)d_in[11];
    const float* dbih = (const float*)d_in[12];
    const float* dbhh = (const float*)d_in[13];
    float* out = (float*)d_out;

    char* ws = (char*)d_ws;
    size_t off = 0;
    auto alloc = [&](size_t bytes) -> char* {
        char* p = ws + off;
        off += (bytes + 255) & ~(size_t)255;
        return p;
    };

    bf16* x_bf    = (bf16*)alloc((size_t)B * S * I * 2);
    bf16* fut_bf  = (bf16*)alloc((size_t)B * F * I * 2);
    bf16* fcw_bf  = (bf16*)alloc((size_t)H * I * 2);
    bf16* ewih_bf = (bf16*)alloc((size_t)2 * G * H * 2);
    bf16* ewhh_bf = (bf16*)alloc((size_t)2 * G * H * 2);
    bf16* dwih_bf = (bf16*)alloc((size_t)2 * G * H * 2);
    bf16* dwhh_bf = (bf16*)alloc((size_t)2 * G * H * 2);
    bf16* xt_bf   = (bf16*)alloc((size_t)B * S * H * 2);
    bf16* h0seq   = (bf16*)alloc((size_t)B * S * H * 2);
    bf16* hD0seq  = (bf16*)alloc((size_t)B * F * H * 2);
    bf16* hbf     = (bf16*)alloc((size_t)2 * 2 * B * H * 2);  // [L][slot][B*H]
    float* hf     = (float*)alloc((size_t)2 * B * H * 4);
    float* cf     = (float*)alloc((size_t)2 * B * H * 4);
    unsigned* bar = (unsigned*)alloc(4 * 64 * sizeof(unsigned)); // 4 counters, 256B apart

    size_t xp32_bytes = (size_t)B * S * G * 4;
    bool xp32 = (ws_size - off) >= xp32_bytes + 4096;
    float* Xf = nullptr; bf16* Xb = nullptr;
    if (xp32) Xf = (float*)alloc(xp32_bytes);
    else      Xb = (bf16*)alloc((size_t)B * S * G * 2);

    auto cvt = [&](const float* s, bf16* d, int n) {
        int blocks = (n / 4 + 255) / 256;
        if (blocks > 4096) blocks = 4096;
        f2b_kernel<<<blocks, 256, 0, stream>>>(s, d, n);
    };
    cvt(x, x_bf, B * S * I);
    cvt(fut, fut_bf, B * F * I);
    cvt(fc_w, fcw_bf, H * I);
    cvt(ewih, ewih_bf, 2 * G * H);
    cvt(ewhh, ewhh_bf, 2 * G * H);
    cvt(dwih, dwih_bf, 2 * G * H);
    cvt(dwhh, dwhh_bf, 2 * G * H);

    init_state_kernel<<<128, 256, 0, stream>>>(eh, ec, hf, cf, hbf, bar);

    auto gemm = [&](const bf16* A, const bf16* W, const float* bias,
                    float* Cf_, bf16* Cb_, int M, int N, int K) {
        gemm_bt<<<dim3(N / 64, M / 64), 256, 0, stream>>>(A, W, bias, Cf_, Cb_, M, N, K);
    };

    // FC: xt = bf16(x @ fc_w^T + fc_b)
    gemm(x_bf, fcw_bf, fc_b, nullptr, xt_bf, B * S, H, I);

    auto run_phase = [&](const bf16* Whh_l, const float* bih_l, const float* bhh_l,
                         int layer, int T, int phase,
                         bf16* seq_base, long seq_stride,
                         float* out_base, long out_stride) {
        lstm_layer_persist<<<32, 256, 0, stream>>>(
            T,
            hbf + (size_t)(layer * 2 + 0) * (B * H),
            hbf + (size_t)(layer * 2 + 1) * (B * H),
            hf + (size_t)layer * B * H, cf + (size_t)layer * B * H,
            Whh_l, Xf, Xb, bih_l, bhh_l,
            seq_base, seq_stride, out_base, out_stride,
            bar + phase * 64);
    };

    // ---- Encoder layer 0 ----
    gemm(xt_bf, ewih_bf, nullptr, Xf, Xb, B * S, G, H);
    run_phase(ewhh_bf, ebih, ebhh, 0, S, 0, h0seq, (long)S * H, nullptr, 0);

    // ---- Encoder layer 1 ---- (sequence discarded; only final state matters)
    gemm(h0seq, ewih_bf + (size_t)G * H, nullptr, Xf, Xb, B * S, G, H);
    run_phase(ewhh_bf + (size_t)G * H, ebih + G, ebhh + G, 1, S, 1, nullptr, 0, nullptr, 0);

    // ---- Decoder layer 0 ---- (initial state = encoder finals; S even -> h in slot 0)
    gemm(fut_bf, dwih_bf, nullptr, Xf, Xb, B * F, G, H);
    run_phase(dwhh_bf, dbih, dbhh, 0, F, 2, hD0seq, (long)F * H, nullptr, 0);

    // ---- Decoder layer 1 ---- writes dec_out directly
    gemm(hD0seq, dwih_bf + (size_t)G * H, nullptr, Xf, Xb, B * F, G, H);
    run_phase(dwhh_bf + (size_t)G * H, dbih + G, dbhh + G, 1, F, 3, nullptr, 0, out, (long)F * H);

    // ---- Final decoder states ----
    tail_kernel<<<128, 256, 0, stream>>>(hf, cf, out);
}

// Round 7
// 3382.809 us; speedup vs baseline: 4.0938x; 1.2993x over previous
//
#include <hip/hip_runtime.h>
#include <hip/hip_bf16.h>

using bf16 = __hip_bfloat16;
typedef short v8s __attribute__((ext_vector_type(8)));   // 8 bf16 = 4 VGPRs
typedef float v4f __attribute__((ext_vector_type(4)));   // MFMA C/D frag

__device__ __forceinline__ float sigmoidf_(float x) {
    return 1.0f / (1.0f + __expf(-x));
}
__device__ __forceinline__ float tanhf_(float x) {
    return 1.0f - 2.0f / (__expf(2.0f * x) + 1.0f);
}
__device__ __forceinline__ unsigned short bfbits(float f) {
    bf16 h = __float2bfloat16(f);
    return *reinterpret_cast<unsigned short*>(&h);
}
__device__ __forceinline__ float bf2f(unsigned short u) {
    bf16 h = *reinterpret_cast<bf16*>(&u);
    return __bfloat162float(h);
}

// ---------------- fp32 -> bf16 converter ----------------
__global__ void f2b_kernel(const float* __restrict__ s, bf16* __restrict__ d, int n) {
    int idx = blockIdx.x * blockDim.x + threadIdx.x;
    int stride = gridDim.x * blockDim.x;
    for (int i = idx * 4; i < n; i += stride * 4) {
        float4 v = *reinterpret_cast<const float4*>(s + i);
        ushort4 u;
        u.x = bfbits(v.x); u.y = bfbits(v.y); u.z = bfbits(v.z); u.w = bfbits(v.w);
        *reinterpret_cast<ushort4*>(d + i) = u;
    }
}

// ---------------- init states + barrier counters ----------------
__global__ void init_state_kernel(const float* __restrict__ eh, const float* __restrict__ ec,
                                  float* __restrict__ hf, float* __restrict__ cf,
                                  bf16* __restrict__ hbf, unsigned* __restrict__ counters) {
    int idx = blockIdx.x * blockDim.x + threadIdx.x;
    if (idx < 4) counters[idx * 64] = 0u;   // phase counters, 256B apart
    if (idx >= 2 * 32 * 512) return;
    int l = idx >> 14;          // / 16384
    int rem = idx & 16383;
    hf[idx] = eh[idx];
    cf[idx] = ec[idx];
    hbf[(l * 2 + 0) * 16384 + rem] = __float2bfloat16(eh[idx]);  // slot a
}

// ---------------- tail: final states -> d_out ----------------
__global__ void tail_kernel(const float* __restrict__ hf, const float* __restrict__ cf,
                            float* __restrict__ out) {
    int idx = blockIdx.x * blockDim.x + threadIdx.x;
    if (idx >= 2 * 32 * 512) return;
    out[1048576 + idx] = hf[idx];
    out[1048576 + 32768 + idx] = cf[idx];
}

// ---------------- bf16 MFMA GEMM: C[M,N] = A[M,K] @ W[N,K]^T (+bias) ----------------
__global__ __launch_bounds__(256) void gemm_bt(
    const bf16* __restrict__ A, const bf16* __restrict__ W,
    const float* __restrict__ bias,
    float* __restrict__ Cf, bf16* __restrict__ Cb,
    int M, int N, int K) {
    __shared__ __align__(16) bf16 As[64][72];
    __shared__ __align__(16) bf16 Bs[64][72];
    const int tid = threadIdx.x;
    const int wave = tid >> 6, lane = tid & 63;
    const int lr = lane & 15, lq = lane >> 4;
    const int m0 = blockIdx.y * 64, n0 = blockIdx.x * 64;

    v4f acc[4];
#pragma unroll
    for (int n = 0; n < 4; ++n) acc[n] = (v4f){0.f, 0.f, 0.f, 0.f};

    for (int k0 = 0; k0 < K; k0 += 64) {
        __syncthreads();
#pragma unroll
        for (int c = tid; c < 512; c += 256) {
            int row = c >> 3, c8 = (c & 7) * 8;
            *reinterpret_cast<v8s*>(&As[row][c8]) =
                *reinterpret_cast<const v8s*>(A + (size_t)(m0 + row) * K + k0 + c8);
            *reinterpret_cast<v8s*>(&Bs[row][c8]) =
                *reinterpret_cast<const v8s*>(W + (size_t)(n0 + row) * K + k0 + c8);
        }
        __syncthreads();
#pragma unroll
        for (int kk = 0; kk < 2; ++kk) {
            v8s a = *reinterpret_cast<const v8s*>(&As[wave * 16 + lr][kk * 32 + lq * 8]);
#pragma unroll
            for (int n = 0; n < 4; ++n) {
                v8s b = *reinterpret_cast<const v8s*>(&Bs[n * 16 + lr][kk * 32 + lq * 8]);
                acc[n] = __builtin_amdgcn_mfma_f32_16x16x32_bf16(a, b, acc[n], 0, 0, 0);
            }
        }
    }
#pragma unroll
    for (int n = 0; n < 4; ++n) {
        int col = n0 + n * 16 + lr;
        float bv = bias ? bias[col] : 0.0f;
#pragma unroll
        for (int r = 0; r < 4; ++r) {
            int row = m0 + wave * 16 + lq * 4 + r;
            float v = acc[n][r] + bv;
            if (Cf) Cf[(size_t)row * N + col] = v;
            if (Cb) Cb[(size_t)row * N + col] = __float2bfloat16(v);
        }
    }
}

// ---------------- persistent 2-layer pipelined LSTM stack ----------------
// 64 WGs x 256 thr, co-resident. WGs 0..31: layer 0 (WG j owns hidden cols
// [j*16,j*16+16), wave w = gate w). WGs 32..63: layer 1, one global step
// behind (at global step s it computes t=s-1, consuming layer 0's h(t) from
// ping-pong slot ((t+1)&1) — disjoint from both same-step writes).
// Layer 1 computes its input projection on the fly: Wih1 @ h0(t).
// Staging: compiler-visible relaxed-agent u64 atomic loads (spill-safe),
// all issued before any LDS write -> pipelined drain, ~one MALL latency.
__global__ __launch_bounds__(256, 1) void lstm2_persist(
    int T,
    bf16* __restrict__ l0a, bf16* __restrict__ l0b,   // layer0 h ping-pong [32*512]
    bf16* __restrict__ l1a, bf16* __restrict__ l1b,   // layer1 h ping-pong
    float* __restrict__ hf, float* __restrict__ cf,    // [2][32*512] fp32 state
    const bf16* __restrict__ Whh0,                     // [2048][512]
    const bf16* __restrict__ Wih1, const bf16* __restrict__ Whh1,
    const float* __restrict__ xpf,                     // layer0 fp32 xp [(b*T+t)*2048]
    const bf16* __restrict__ xpb,                      // layer0 bf16 xp (alt)
    const float* __restrict__ bih0, const float* __restrict__ bhh0,
    const float* __restrict__ bih1, const float* __restrict__ bhh1,
    float* __restrict__ outf, long out_stride_b,       // layer1 fp32 h seq (or null)
    unsigned* __restrict__ bar)
{
    __shared__ __align__(16) bf16 hs_h[32][520];   // own h(t-1); +8 pad
    __shared__ __align__(16) bf16 hs_x[32][520];   // layer1: h0(t)
    __shared__ float gs[4][32][16];
    __shared__ float bias_s[4][16];

    const int tid = threadIdx.x;
    const int layer = blockIdx.x >> 5;
    const int jj = blockIdx.x & 31;
    const int wave = tid >> 6, lane = tid & 63;
    const int lr = lane & 15, lq = lane >> 4;
    const int hc0 = jj * 16;

    const float* bih_l = layer ? bih1 : bih0;
    const float* bhh_l = layer ? bhh1 : bhh0;
    if (tid < 64) {
        int g = tid >> 4, col = tid & 15;
        bias_s[g][col] = bih_l[g * 512 + hc0 + col] + bhh_l[g * 512 + hc0 + col];
    }

    // pointwise ownership: batch pb, cols pc & pc+1 (c register-resident)
    const int pb = tid >> 3;
    const int pc = (tid & 7) * 2;
    const int pgc = hc0 + pc;

    float* hf_l = hf + (size_t)layer * 16384;
    float* cf_l = cf + (size_t)layer * 16384;
    float c0, c1;
    {
        size_t sidx = (size_t)pb * 512 + pgc;
        c0 = cf_l[sidx]; c1 = cf_l[sidx + 1];
    }

    // weights: Whh slice always; Wih slice for layer 1 (compiler may cache in
    // regs or re-read from L2 — both correct)
    v8s breg_hh[16], breg_ih[16];
    {
        const bf16* Whh_l = layer ? Whh1 : Whh0;
        const bf16* wrow = Whh_l + (size_t)(wave * 512 + hc0 + lr) * 512 + lq * 8;
#pragma unroll
        for (int kk = 0; kk < 16; ++kk)
            breg_hh[kk] = *reinterpret_cast<const v8s*>(wrow + kk * 32);
        if (layer) {
            const bf16* wrow2 = Wih1 + (size_t)(wave * 512 + hc0 + lr) * 512 + lq * 8;
#pragma unroll
            for (int kk = 0; kk < 16; ++kk)
                breg_ih[kk] = *reinterpret_cast<const v8s*>(wrow2 + kk * 32);
        }
    }
    __syncthreads();

    // staging geometry: thread tid covers v8s at element tid*8 + i*2048
    // = u64 indices tid*2 + i*512 (+1), LDS row (tid>>6)+4i, col (tid*8)&511
    const int st_row = tid >> 6;
    const int st_col = (tid * 8) & 511;

    auto load_xp = [&](int t, float* xv) {
        if (xpf) {
            const float* xp = xpf + ((size_t)pb * T + t) * 2048;
            float2 a = *reinterpret_cast<const float2*>(xp + pgc);
            float2 b = *reinterpret_cast<const float2*>(xp + 512 + pgc);
            float2 c = *reinterpret_cast<const float2*>(xp + 1024 + pgc);
            float2 d = *reinterpret_cast<const float2*>(xp + 1536 + pgc);
            xv[0] = a.x; xv[1] = a.y; xv[2] = b.x; xv[3] = b.y;
            xv[4] = c.x; xv[5] = c.y; xv[6] = d.x; xv[7] = d.y;
        } else {
            const bf16* xp = xpb + ((size_t)pb * T + t) * 2048;
            unsigned a = *reinterpret_cast<const unsigned*>(xp + pgc);
            unsigned b = *reinterpret_cast<const unsigned*>(xp + 512 + pgc);
            unsigned c = *reinterpret_cast<const unsigned*>(xp + 1024 + pgc);
            unsigned d = *reinterpret_cast<const unsigned*>(xp + 1536 + pgc);
            xv[0] = bf2f(a & 0xffff); xv[1] = bf2f(a >> 16);
            xv[2] = bf2f(b & 0xffff); xv[3] = bf2f(b >> 16);
            xv[4] = bf2f(c & 0xffff); xv[5] = bf2f(c >> 16);
            xv[6] = bf2f(d & 0xffff); xv[7] = bf2f(d >> 16);
        }
    };

    float xcur[8];
    if (!layer) load_xp(0, xcur);

    bf16* mya = layer ? l1a : l0a;
    bf16* myb = layer ? l1b : l0b;

    for (int s = 0; s <= T; ++s) {
        const int t = layer ? s - 1 : s;
        const bool active = layer ? (s >= 1) : (s < T);
        if (active) {
            const bf16* hin = (t & 1) ? myb : mya;
            bf16* hout      = (t & 1) ? mya : myb;

            // ---- stage inputs -> LDS (coherent u64 loads, issued first) ----
            {
                const unsigned long long* srcH =
                    reinterpret_cast<const unsigned long long*>(hin);
                unsigned long long rh[16];
#pragma unroll
                for (int i = 0; i < 8; ++i) {
                    rh[2 * i] = __hip_atomic_load(srcH + tid * 2 + i * 512,
                                    __ATOMIC_RELAXED, __HIP_MEMORY_SCOPE_AGENT);
                    rh[2 * i + 1] = __hip_atomic_load(srcH + tid * 2 + i * 512 + 1,
                                    __ATOMIC_RELAXED, __HIP_MEMORY_SCOPE_AGENT);
                }
                if (layer) {
                    const bf16* l0src = ((t + 1) & 1) ? l0b : l0a;   // layer0 h(t)
                    const unsigned long long* srcX =
                        reinterpret_cast<const unsigned long long*>(l0src);
                    unsigned long long rx[16];
#pragma unroll
                    for (int i = 0; i < 8; ++i) {
                        rx[2 * i] = __hip_atomic_load(srcX + tid * 2 + i * 512,
                                        __ATOMIC_RELAXED, __HIP_MEMORY_SCOPE_AGENT);
                        rx[2 * i + 1] = __hip_atomic_load(srcX + tid * 2 + i * 512 + 1,
                                        __ATOMIC_RELAXED, __HIP_MEMORY_SCOPE_AGENT);
                    }
#pragma unroll
                    for (int i = 0; i < 8; ++i) {
                        union { unsigned long long u[2]; v8s v; } w;
                        w.u[0] = rx[2 * i]; w.u[1] = rx[2 * i + 1];
                        *reinterpret_cast<v8s*>(&hs_x[st_row + 4 * i][st_col]) = w.v;
                    }
                }
#pragma unroll
                for (int i = 0; i < 8; ++i) {
                    union { unsigned long long u[2]; v8s v; } w;
                    w.u[0] = rh[2 * i]; w.u[1] = rh[2 * i + 1];
                    *reinterpret_cast<v8s*>(&hs_h[st_row + 4 * i][st_col]) = w.v;
                }
            }
            __syncthreads();

            // ---- gate GEMM from LDS (layer1: x-proj + h-proj) ----
            v4f acc0 = (v4f){0.f, 0.f, 0.f, 0.f};
            v4f acc1 = (v4f){0.f, 0.f, 0.f, 0.f};
            if (layer) {
#pragma unroll
                for (int kk = 0; kk < 16; ++kk) {
                    v8s a0 = *reinterpret_cast<const v8s*>(&hs_x[lr][lq * 8 + kk * 32]);
                    v8s a1 = *reinterpret_cast<const v8s*>(&hs_x[16 + lr][lq * 8 + kk * 32]);
                    acc0 = __builtin_amdgcn_mfma_f32_16x16x32_bf16(a0, breg_ih[kk], acc0, 0, 0, 0);
                    acc1 = __builtin_amdgcn_mfma_f32_16x16x32_bf16(a1, breg_ih[kk], acc1, 0, 0, 0);
                }
            }
#pragma unroll
            for (int kk = 0; kk < 16; ++kk) {
                v8s a0 = *reinterpret_cast<const v8s*>(&hs_h[lr][lq * 8 + kk * 32]);
                v8s a1 = *reinterpret_cast<const v8s*>(&hs_h[16 + lr][lq * 8 + kk * 32]);
                acc0 = __builtin_amdgcn_mfma_f32_16x16x32_bf16(a0, breg_hh[kk], acc0, 0, 0, 0);
                acc1 = __builtin_amdgcn_mfma_f32_16x16x32_bf16(a1, breg_hh[kk], acc1, 0, 0, 0);
            }
#pragma unroll
            for (int r2 = 0; r2 < 4; ++r2) {
                gs[wave][lq * 4 + r2][lr]      = acc0[r2];
                gs[wave][16 + lq * 4 + r2][lr] = acc1[r2];
            }
            __syncthreads();

            // ---- pointwise: this thread's (pb, pc..pc+1) ----
            float xi0 = layer ? 0.f : xcur[0], xi1 = layer ? 0.f : xcur[1];
            float xf0 = layer ? 0.f : xcur[2], xf1 = layer ? 0.f : xcur[3];
            float xg0 = layer ? 0.f : xcur[4], xg1 = layer ? 0.f : xcur[5];
            float xo0 = layer ? 0.f : xcur[6], xo1 = layer ? 0.f : xcur[7];

            float gi0 = gs[0][pb][pc]     + xi0 + bias_s[0][pc];
            float gi1 = gs[0][pb][pc + 1] + xi1 + bias_s[0][pc + 1];
            float gf0 = gs[1][pb][pc]     + xf0 + bias_s[1][pc];
            float gf1 = gs[1][pb][pc + 1] + xf1 + bias_s[1][pc + 1];
            float gg0 = gs[2][pb][pc]     + xg0 + bias_s[2][pc];
            float gg1 = gs[2][pb][pc + 1] + xg1 + bias_s[2][pc + 1];
            float go0 = gs[3][pb][pc]     + xo0 + bias_s[3][pc];
            float go1 = gs[3][pb][pc + 1] + xo1 + bias_s[3][pc + 1];

            c0 = sigmoidf_(gf0) * c0 + sigmoidf_(gi0) * tanhf_(gg0);
            c1 = sigmoidf_(gf1) * c1 + sigmoidf_(gi1) * tanhf_(gg1);
            float h0v = sigmoidf_(go0) * tanhf_(c0);
            float h1v = sigmoidf_(go1) * tanhf_(c1);

            unsigned hp = (unsigned)bfbits(h0v) | ((unsigned)bfbits(h1v) << 16);
            __hip_atomic_store(reinterpret_cast<unsigned*>(hout + (size_t)pb * 512 + pgc),
                               hp, __ATOMIC_RELAXED, __HIP_MEMORY_SCOPE_AGENT);
            if (layer && outf) {
                float2 hv; hv.x = h0v; hv.y = h1v;
                *reinterpret_cast<float2*>(outf + (size_t)pb * out_stride_b + (size_t)t * 512 + pgc) = hv;
            }
            if (t == T - 1) {
                size_t sidx = (size_t)pb * 512 + pgc;
                hf_l[sidx] = h0v; hf_l[sidx + 1] = h1v;
                cf_l[sidx] = c0;  cf_l[sidx + 1] = c1;
            }

            // layer0: prefetch xp(t+1); latency drains in the barrier's vmcnt(0)
            if (!layer && t + 1 < T) load_xp(t + 1, xcur);
        }

        // ---- fence-free grid barrier (skip after the final step) ----
        if (s < T) {
            __syncthreads();   // drains vmcnt(0): h stores agent-visible
            if (tid == 0) {
                __hip_atomic_fetch_add(bar, 1u, __ATOMIC_RELAXED, __HIP_MEMORY_SCOPE_AGENT);
                unsigned target = 64u * (unsigned)(s + 1);
                while (__hip_atomic_load(bar, __ATOMIC_RELAXED, __HIP_MEMORY_SCOPE_AGENT) < target) {}
            }
            __syncthreads();
        }
    }
}

// ---------------- host orchestration ----------------
extern "C" void kernel_launch(void* const* d_in, const int* in_sizes, int n_in,
                              void* d_out, int out_size, void* d_ws, size_t ws_size,
                              hipStream_t stream) {
    constexpr int B = 32, S = 512, F = 64, I = 512, H = 512, G = 2048;

    const float* x    = (const float*)d_in[0];
    const float* fut  = (const float*)d_in[1];
    const float* eh   = (const float*)d_in[2];
    const float* ec   = (const float*)d_in[3];
    const float* fc_w = (const float*)d_in[4];
    const float* fc_b = (const float*)d_in[5];
    const float* ewih = (const float*)d_in[6];
    const float* ewhh = (const float*)d_in[7];
    const float* ebih = (const float*)d_in[8];
    const float* ebhh = (const float*)d_in[9];
    const float* dwih = (const float*)d_in[10];
    const float* dwhh = (const float*)d_in[11];
    const float* dbih = (const float*)d_in[12];
    const float* dbhh = (const float*)d_in[13];
    float* out = (float*)d_out;

    char* ws = (char*)d_ws;
    size_t off = 0;
    auto alloc = [&](size_t bytes) -> char* {
        char* p = ws + off;
        off += (bytes + 255) & ~(size_t)255;
        return p;
    };

    bf16* x_bf    = (bf16*)alloc((size_t)B * S * I * 2);
    bf16* fut_bf  = (bf16*)alloc((size_t)B * F * I * 2);
    bf16* fcw_bf  = (bf16*)alloc((size_t)H * I * 2);
    bf16* ewih_bf = (bf16*)alloc((size_t)2 * G * H * 2);
    bf16* ewhh_bf = (bf16*)alloc((size_t)2 * G * H * 2);
    bf16* dwih_bf = (bf16*)alloc((size_t)2 * G * H * 2);
    bf16* dwhh_bf = (bf16*)alloc((size_t)2 * G * H * 2);
    bf16* xt_bf   = (bf16*)alloc((size_t)B * S * H * 2);
    bf16* hbf     = (bf16*)alloc((size_t)2 * 2 * B * H * 2);  // [L][slot][B*H]
    float* hf     = (float*)alloc((size_t)2 * B * H * 4);
    float* cf     = (float*)alloc((size_t)2 * B * H * 4);
    unsigned* bar = (unsigned*)alloc(4 * 64 * sizeof(unsigned)); // counters, 256B apart

    size_t xp32_bytes = (size_t)B * S * G * 4;
    bool xp32 = (ws_size - off) >= xp32_bytes + 4096;
    float* Xf = nullptr; bf16* Xb = nullptr;
    if (xp32) Xf = (float*)alloc(xp32_bytes);
    else      Xb = (bf16*)alloc((size_t)B * S * G * 2);

    auto cvt = [&](const float* s, bf16* d, int n) {
        int blocks = (n / 4 + 255) / 256;
        if (blocks > 4096) blocks = 4096;
        f2b_kernel<<<blocks, 256, 0, stream>>>(s, d, n);
    };
    cvt(x, x_bf, B * S * I);
    cvt(fut, fut_bf, B * F * I);
    cvt(fc_w, fcw_bf, H * I);
    cvt(ewih, ewih_bf, 2 * G * H);
    cvt(ewhh, ewhh_bf, 2 * G * H);
    cvt(dwih, dwih_bf, 2 * G * H);
    cvt(dwhh, dwhh_bf, 2 * G * H);

    init_state_kernel<<<128, 256, 0, stream>>>(eh, ec, hf, cf, hbf, bar);

    auto gemm = [&](const bf16* A, const bf16* W, const float* bias,
                    float* Cf_, bf16* Cb_, int M, int N, int K) {
        gemm_bt<<<dim3(N / 64, M / 64), 256, 0, stream>>>(A, W, bias, Cf_, Cb_, M, N, K);
    };

    // FC: xt = bf16(x @ fc_w^T + fc_b)
    gemm(x_bf, fcw_bf, fc_b, nullptr, xt_bf, B * S, H, I);

    // ---- Encoder: xp for layer 0 only, then pipelined 2-layer persist ----
    gemm(xt_bf, ewih_bf, nullptr, Xf, Xb, B * S, G, H);
    lstm2_persist<<<64, 256, 0, stream>>>(
        S,
        hbf + 0 * 16384, hbf + 1 * 16384,    // layer0 ping-pong
        hbf + 2 * 16384, hbf + 3 * 16384,    // layer1 ping-pong
        hf, cf,
        ewhh_bf,                              // Whh0
        ewih_bf + (size_t)G * H,              // Wih1
        ewhh_bf + (size_t)G * H,              // Whh1
        Xf, Xb,
        ebih, ebhh, ebih + G, ebhh + G,
        nullptr, 0,
        bar + 0 * 64);

    // ---- Decoder: xp for layer 0 only, then pipelined 2-layer persist ----
    gemm(fut_bf, dwih_bf, nullptr, Xf, Xb, B * F, G, H);
    lstm2_persist<<<64, 256, 0, stream>>>(
        F,
        hbf + 0 * 16384, hbf + 1 * 16384,
        hbf + 2 * 16384, hbf + 3 * 16384,
        hf, cf,
        dwhh_bf,
        dwih_bf + (size_t)G * H,
        dwhh_bf + (size_t)G * H,
        Xf, Xb,
        dbih, dbhh, dbih + G, dbhh + G,
        out, (long)F * H,                     // dec_out [B,F,H] fp32
        bar + 1 * 64);

    // ---- Final decoder states ----
    tail_kernel<<<128, 256, 0, stream>>>(hf, cf, out);
}

// Round 8
// 3166.824 us; speedup vs baseline: 4.3731x; 1.0682x over previous
//
#include <hip/hip_runtime.h>
#include <hip/hip_bf16.h>

using bf16 = __hip_bfloat16;
typedef short v8s __attribute__((ext_vector_type(8)));   // 8 bf16 = 4 VGPRs
typedef float v4f __attribute__((ext_vector_type(4)));   // MFMA C/D frag

__device__ __forceinline__ float sigmoidf_(float x) {
    return 1.0f / (1.0f + __expf(-x));
}
__device__ __forceinline__ float tanhf_(float x) {
    return 1.0f - 2.0f / (__expf(2.0f * x) + 1.0f);
}
__device__ __forceinline__ unsigned short bfbits(float f) {
    bf16 h = __float2bfloat16(f);
    return *reinterpret_cast<unsigned short*>(&h);
}
__device__ __forceinline__ float bf2f(unsigned short u) {
    bf16 h = *reinterpret_cast<bf16*>(&u);
    return __bfloat162float(h);
}

// ---------------- fp32 -> bf16 converter ----------------
__global__ void f2b_kernel(const float* __restrict__ s, bf16* __restrict__ d, int n) {
    int idx = blockIdx.x * blockDim.x + threadIdx.x;
    int stride = gridDim.x * blockDim.x;
    for (int i = idx * 4; i < n; i += stride * 4) {
        float4 v = *reinterpret_cast<const float4*>(s + i);
        ushort4 u;
        u.x = bfbits(v.x); u.y = bfbits(v.y); u.z = bfbits(v.z); u.w = bfbits(v.w);
        *reinterpret_cast<ushort4*>(d + i) = u;
    }
}

// ---------------- init states + barrier flags ----------------
__global__ void init_state_kernel(const float* __restrict__ eh, const float* __restrict__ ec,
                                  float* __restrict__ hf, float* __restrict__ cf,
                                  bf16* __restrict__ hbf, unsigned* __restrict__ flags) {
    int idx = blockIdx.x * blockDim.x + threadIdx.x;
    if (idx < 128) flags[idx] = 0u;   // 2 phases x 64 WG flags
    if (idx >= 2 * 32 * 512) return;
    int l = idx >> 14;          // / 16384
    int rem = idx & 16383;
    hf[idx] = eh[idx];
    cf[idx] = ec[idx];
    hbf[(l * 2 + 0) * 16384 + rem] = __float2bfloat16(eh[idx]);  // slot a
}

// ---------------- tail: final states -> d_out ----------------
__global__ void tail_kernel(const float* __restrict__ hf, const float* __restrict__ cf,
                            float* __restrict__ out) {
    int idx = blockIdx.x * blockDim.x + threadIdx.x;
    if (idx >= 2 * 32 * 512) return;
    out[1048576 + idx] = hf[idx];
    out[1048576 + 32768 + idx] = cf[idx];
}

// ---------------- bf16 MFMA GEMM: C[M,N] = A[M,K] @ W[N,K]^T (+bias) ----------------
__global__ __launch_bounds__(256) void gemm_bt(
    const bf16* __restrict__ A, const bf16* __restrict__ W,
    const float* __restrict__ bias,
    float* __restrict__ Cf, bf16* __restrict__ Cb,
    int M, int N, int K) {
    __shared__ __align__(16) bf16 As[64][72];
    __shared__ __align__(16) bf16 Bs[64][72];
    const int tid = threadIdx.x;
    const int wave = tid >> 6, lane = tid & 63;
    const int lr = lane & 15, lq = lane >> 4;
    const int m0 = blockIdx.y * 64, n0 = blockIdx.x * 64;

    v4f acc[4];
#pragma unroll
    for (int n = 0; n < 4; ++n) acc[n] = (v4f){0.f, 0.f, 0.f, 0.f};

    for (int k0 = 0; k0 < K; k0 += 64) {
        __syncthreads();
#pragma unroll
        for (int c = tid; c < 512; c += 256) {
            int row = c >> 3, c8 = (c & 7) * 8;
            *reinterpret_cast<v8s*>(&As[row][c8]) =
                *reinterpret_cast<const v8s*>(A + (size_t)(m0 + row) * K + k0 + c8);
            *reinterpret_cast<v8s*>(&Bs[row][c8]) =
                *reinterpret_cast<const v8s*>(W + (size_t)(n0 + row) * K + k0 + c8);
        }
        __syncthreads();
#pragma unroll
        for (int kk = 0; kk < 2; ++kk) {
            v8s a = *reinterpret_cast<const v8s*>(&As[wave * 16 + lr][kk * 32 + lq * 8]);
#pragma unroll
            for (int n = 0; n < 4; ++n) {
                v8s b = *reinterpret_cast<const v8s*>(&Bs[n * 16 + lr][kk * 32 + lq * 8]);
                acc[n] = __builtin_amdgcn_mfma_f32_16x16x32_bf16(a, b, acc[n], 0, 0, 0);
            }
        }
    }
#pragma unroll
    for (int n = 0; n < 4; ++n) {
        int col = n0 + n * 16 + lr;
        float bv = bias ? bias[col] : 0.0f;
#pragma unroll
        for (int r = 0; r < 4; ++r) {
            int row = m0 + wave * 16 + lq * 4 + r;
            float v = acc[n][r] + bv;
            if (Cf) Cf[(size_t)row * N + col] = v;
            if (Cb) Cb[(size_t)row * N + col] = __float2bfloat16(v);
        }
    }
}

// ---------------- persistent 2-layer pipelined LSTM stack ----------------
// 64 WGs x 256 thr, co-resident. WGs 0..31: layer 0 (WG j owns hidden cols
// [j*16,j*16+16), wave w = gate w). WGs 32..63: layer 1, one global step
// behind, consuming layer 0's h(t) from ping-pong slot ((t+1)&1).
// Layer 1: Wih1 slice staged in LDS (64 KB, loaded once) so only Whh1 needs
// registers (64 VGPRs — keeps the allocator from evicting weights).
// Barrier: per-WG flag words (parallel stores) + one coalesced 64-lane
// coherent poll in wave 0 — no atomic-RMW serialization.
__global__ __launch_bounds__(256, 1) void lstm2_persist(
    int T,
    bf16* __restrict__ l0a, bf16* __restrict__ l0b,   // layer0 h ping-pong [32*512]
    bf16* __restrict__ l1a, bf16* __restrict__ l1b,   // layer1 h ping-pong
    float* __restrict__ hf, float* __restrict__ cf,    // [2][32*512] fp32 state
    const bf16* __restrict__ Whh0,                     // [2048][512]
    const bf16* __restrict__ Wih1, const bf16* __restrict__ Whh1,
    const float* __restrict__ xpf,                     // layer0 fp32 xp [(b*T+t)*2048]
    const bf16* __restrict__ xpb,                      // layer0 bf16 xp (alt)
    const float* __restrict__ bih0, const float* __restrict__ bhh0,
    const float* __restrict__ bih1, const float* __restrict__ bhh1,
    float* __restrict__ outf, long out_stride_b,       // layer1 fp32 h seq (or null)
    unsigned* __restrict__ flags)                      // 64 per-WG step flags
{
    __shared__ __align__(16) bf16 hs_h[32][520];      // own h(t-1); +8 pad
    __shared__ __align__(16) bf16 hs_x[32][520];      // layer1: h0(t)
    __shared__ __align__(16) bf16 wih_s[4][16][520];  // layer1: Wih1 slice (pad 520)
    __shared__ float gs[4][32][16];
    __shared__ float bias_s[4][16];

    const int tid = threadIdx.x;
    const int layer = blockIdx.x >> 5;
    const int jj = blockIdx.x & 31;
    const int wave = tid >> 6, lane = tid & 63;
    const int lr = lane & 15, lq = lane >> 4;
    const int hc0 = jj * 16;

    const float* bih_l = layer ? bih1 : bih0;
    const float* bhh_l = layer ? bhh1 : bhh0;
    if (tid < 64) {
        int g = tid >> 4, col = tid & 15;
        bias_s[g][col] = bih_l[g * 512 + hc0 + col] + bhh_l[g * 512 + hc0 + col];
    }

    // pointwise ownership: batch pb, cols pc & pc+1 (c register-resident)
    const int pb = tid >> 3;
    const int pc = (tid & 7) * 2;
    const int pgc = hc0 + pc;

    float* hf_l = hf + (size_t)layer * 16384;
    float* cf_l = cf + (size_t)layer * 16384;
    float c0, c1;
    {
        size_t sidx = (size_t)pb * 512 + pgc;
        c0 = cf_l[sidx]; c1 = cf_l[sidx + 1];
    }

    // Whh slice pinned in registers (64 VGPRs). Layer1's Wih goes to LDS.
    v8s breg_hh[16];
    {
        const bf16* Whh_l = layer ? Whh1 : Whh0;
        const bf16* wrow = Whh_l + (size_t)(wave * 512 + hc0 + lr) * 512 + lq * 8;
#pragma unroll
        for (int kk = 0; kk < 16; ++kk)
            breg_hh[kk] = *reinterpret_cast<const v8s*>(wrow + kk * 32);
    }
    if (layer) {
        // stage Wih1 gate-slice [4][16][512] -> LDS, once (4096 v8s / 256 thr)
        for (int i = tid; i < 4096; i += 256) {
            int g = i >> 10;            // v8s 64 per row, 16 rows per gate
            int r = (i >> 6) & 15;
            int c8 = i & 63;
            *reinterpret_cast<v8s*>(&wih_s[g][r][c8 * 8]) =
                *reinterpret_cast<const v8s*>(
                    Wih1 + (size_t)(g * 512 + hc0 + r) * 512 + c8 * 8);
        }
    }
    __syncthreads();

    // staging geometry: thread tid covers v8s at element tid*8 + i*2048,
    // LDS row (tid>>6)+4i, col (tid*8)&511
    const int st_row = tid >> 6;
    const int st_col = (tid * 8) & 511;

    auto load_xp = [&](int t, float* xv) {
        if (xpf) {
            const float* xp = xpf + ((size_t)pb * T + t) * 2048;
            float2 a = *reinterpret_cast<const float2*>(xp + pgc);
            float2 b = *reinterpret_cast<const float2*>(xp + 512 + pgc);
            float2 c = *reinterpret_cast<const float2*>(xp + 1024 + pgc);
            float2 d = *reinterpret_cast<const float2*>(xp + 1536 + pgc);
            xv[0] = a.x; xv[1] = a.y; xv[2] = b.x; xv[3] = b.y;
            xv[4] = c.x; xv[5] = c.y; xv[6] = d.x; xv[7] = d.y;
        } else {
            const bf16* xp = xpb + ((size_t)pb * T + t) * 2048;
            unsigned a = *reinterpret_cast<const unsigned*>(xp + pgc);
            unsigned b = *reinterpret_cast<const unsigned*>(xp + 512 + pgc);
            unsigned c = *reinterpret_cast<const unsigned*>(xp + 1024 + pgc);
            unsigned d = *reinterpret_cast<const unsigned*>(xp + 1536 + pgc);
            xv[0] = bf2f(a & 0xffff); xv[1] = bf2f(a >> 16);
            xv[2] = bf2f(b & 0xffff); xv[3] = bf2f(b >> 16);
            xv[4] = bf2f(c & 0xffff); xv[5] = bf2f(c >> 16);
            xv[6] = bf2f(d & 0xffff); xv[7] = bf2f(d >> 16);
        }
    };

    float xcur[8];
    if (!layer) load_xp(0, xcur);

    bf16* mya = layer ? l1a : l0a;
    bf16* myb = layer ? l1b : l0b;

    for (int s = 0; s <= T; ++s) {
        const int t = layer ? s - 1 : s;
        const bool active = layer ? (s >= 1) : (s < T);
        if (active) {
            const bf16* hin = (t & 1) ? myb : mya;
            bf16* hout      = (t & 1) ? mya : myb;

            // ---- stage inputs -> LDS (coherent u64 loads, issued first) ----
            {
                const unsigned long long* srcH =
                    reinterpret_cast<const unsigned long long*>(hin);
                unsigned long long rh[16];
#pragma unroll
                for (int i = 0; i < 8; ++i) {
                    rh[2 * i] = __hip_atomic_load(srcH + tid * 2 + i * 512,
                                    __ATOMIC_RELAXED, __HIP_MEMORY_SCOPE_AGENT);
                    rh[2 * i + 1] = __hip_atomic_load(srcH + tid * 2 + i * 512 + 1,
                                    __ATOMIC_RELAXED, __HIP_MEMORY_SCOPE_AGENT);
                }
                if (layer) {
                    const bf16* l0src = ((t + 1) & 1) ? l0b : l0a;   // layer0 h(t)
                    const unsigned long long* srcX =
                        reinterpret_cast<const unsigned long long*>(l0src);
                    unsigned long long rx[16];
#pragma unroll
                    for (int i = 0; i < 8; ++i) {
                        rx[2 * i] = __hip_atomic_load(srcX + tid * 2 + i * 512,
                                        __ATOMIC_RELAXED, __HIP_MEMORY_SCOPE_AGENT);
                        rx[2 * i + 1] = __hip_atomic_load(srcX + tid * 2 + i * 512 + 1,
                                        __ATOMIC_RELAXED, __HIP_MEMORY_SCOPE_AGENT);
                    }
#pragma unroll
                    for (int i = 0; i < 8; ++i) {
                        union { unsigned long long u[2]; v8s v; } w;
                        w.u[0] = rx[2 * i]; w.u[1] = rx[2 * i + 1];
                        *reinterpret_cast<v8s*>(&hs_x[st_row + 4 * i][st_col]) = w.v;
                    }
                }
#pragma unroll
                for (int i = 0; i < 8; ++i) {
                    union { unsigned long long u[2]; v8s v; } w;
                    w.u[0] = rh[2 * i]; w.u[1] = rh[2 * i + 1];
                    *reinterpret_cast<v8s*>(&hs_h[st_row + 4 * i][st_col]) = w.v;
                }
            }
            __syncthreads();

            // ---- gate GEMM from LDS (layer1: x-proj from LDS weights) ----
            v4f acc0 = (v4f){0.f, 0.f, 0.f, 0.f};
            v4f acc1 = (v4f){0.f, 0.f, 0.f, 0.f};
            if (layer) {
#pragma unroll
                for (int kk = 0; kk < 16; ++kk) {
                    v8s bx = *reinterpret_cast<const v8s*>(&wih_s[wave][lr][lq * 8 + kk * 32]);
                    v8s a0 = *reinterpret_cast<const v8s*>(&hs_x[lr][lq * 8 + kk * 32]);
                    v8s a1 = *reinterpret_cast<const v8s*>(&hs_x[16 + lr][lq * 8 + kk * 32]);
                    acc0 = __builtin_amdgcn_mfma_f32_16x16x32_bf16(a0, bx, acc0, 0, 0, 0);
                    acc1 = __builtin_amdgcn_mfma_f32_16x16x32_bf16(a1, bx, acc1, 0, 0, 0);
                }
            }
#pragma unroll
            for (int kk = 0; kk < 16; ++kk) {
                v8s a0 = *reinterpret_cast<const v8s*>(&hs_h[lr][lq * 8 + kk * 32]);
                v8s a1 = *reinterpret_cast<const v8s*>(&hs_h[16 + lr][lq * 8 + kk * 32]);
                acc0 = __builtin_amdgcn_mfma_f32_16x16x32_bf16(a0, breg_hh[kk], acc0, 0, 0, 0);
                acc1 = __builtin_amdgcn_mfma_f32_16x16x32_bf16(a1, breg_hh[kk], acc1, 0, 0, 0);
            }
#pragma unroll
            for (int r2 = 0; r2 < 4; ++r2) {
                gs[wave][lq * 4 + r2][lr]      = acc0[r2];
                gs[wave][16 + lq * 4 + r2][lr] = acc1[r2];
            }
            __syncthreads();

            // ---- pointwise: this thread's (pb, pc..pc+1) ----
            float xi0 = layer ? 0.f : xcur[0], xi1 = layer ? 0.f : xcur[1];
            float xf0 = layer ? 0.f : xcur[2], xf1 = layer ? 0.f : xcur[3];
            float xg0 = layer ? 0.f : xcur[4], xg1 = layer ? 0.f : xcur[5];
            float xo0 = layer ? 0.f : xcur[6], xo1 = layer ? 0.f : xcur[7];

            float gi0 = gs[0][pb][pc]     + xi0 + bias_s[0][pc];
            float gi1 = gs[0][pb][pc + 1] + xi1 + bias_s[0][pc + 1];
            float gf0 = gs[1][pb][pc]     + xf0 + bias_s[1][pc];
            float gf1 = gs[1][pb][pc + 1] + xf1 + bias_s[1][pc + 1];
            float gg0 = gs[2][pb][pc]     + xg0 + bias_s[2][pc];
            float gg1 = gs[2][pb][pc + 1] + xg1 + bias_s[2][pc + 1];
            float go0 = gs[3][pb][pc]     + xo0 + bias_s[3][pc];
            float go1 = gs[3][pb][pc + 1] + xo1 + bias_s[3][pc + 1];

            c0 = sigmoidf_(gf0) * c0 + sigmoidf_(gi0) * tanhf_(gg0);
            c1 = sigmoidf_(gf1) * c1 + sigmoidf_(gi1) * tanhf_(gg1);
            float h0v = sigmoidf_(go0) * tanhf_(c0);
            float h1v = sigmoidf_(go1) * tanhf_(c1);

            unsigned hp = (unsigned)bfbits(h0v) | ((unsigned)bfbits(h1v) << 16);
            __hip_atomic_store(reinterpret_cast<unsigned*>(hout + (size_t)pb * 512 + pgc),
                               hp, __ATOMIC_RELAXED, __HIP_MEMORY_SCOPE_AGENT);
            if (layer && outf) {
                float2 hv; hv.x = h0v; hv.y = h1v;
                *reinterpret_cast<float2*>(outf + (size_t)pb * out_stride_b + (size_t)t * 512 + pgc) = hv;
            }
            if (t == T - 1) {
                size_t sidx = (size_t)pb * 512 + pgc;
                hf_l[sidx] = h0v; hf_l[sidx + 1] = h1v;
                cf_l[sidx] = c0;  cf_l[sidx + 1] = c1;
            }

            // layer0: prefetch xp(t+1); latency drains in the barrier's vmcnt(0)
            if (!layer && t + 1 < T) load_xp(t + 1, xcur);
        }

        // ---- flag-array grid barrier (no atomic RMW; skip after final step) ----
        if (s < T) {
            __syncthreads();   // drains vmcnt(0): h stores agent-visible before flag
            if (tid == 0)
                __hip_atomic_store(&flags[blockIdx.x], (unsigned)(s + 1),
                                   __ATOMIC_RELAXED, __HIP_MEMORY_SCOPE_AGENT);
            if (tid < 64) {
                for (;;) {
                    unsigned v = __hip_atomic_load(&flags[tid],
                                     __ATOMIC_RELAXED, __HIP_MEMORY_SCOPE_AGENT);
                    if (__all(v >= (unsigned)(s + 1))) break;
                }
            }
            __syncthreads();
        }
    }
}

// ---------------- host orchestration ----------------
extern "C" void kernel_launch(void* const* d_in, const int* in_sizes, int n_in,
                              void* d_out, int out_size, void* d_ws, size_t ws_size,
                              hipStream_t stream) {
    constexpr int B = 32, S = 512, F = 64, I = 512, H = 512, G = 2048;

    const float* x    = (const float*)d_in[0];
    const float* fut  = (const float*)d_in[1];
    const float* eh   = (const float*)d_in[2];
    const float* ec   = (const float*)d_in[3];
    const float* fc_w = (const float*)d_in[4];
    const float* fc_b = (const float*)d_in[5];
    const float* ewih = (const float*)d_in[6];
    const float* ewhh = (const float*)d_in[7];
    const float* ebih = (const float*)d_in[8];
    const float* ebhh = (const float*)d_in[9];
    const float* dwih = (const float*)d_in[10];
    const float* dwhh = (const float*)d_in[11];
    const float* dbih = (const float*)d_in[12];
    const float* dbhh = (const float*)d_in[13];
    float* out = (float*)d_out;

    char* ws = (char*)d_ws;
    size_t off = 0;
    auto alloc = [&](size_t bytes) -> char* {
        char* p = ws + off;
        off += (bytes + 255) & ~(size_t)255;
        return p;
    };

    bf16* x_bf    = (bf16*)alloc((size_t)B * S * I * 2);
    bf16* fut_bf  = (bf16*)alloc((size_t)B * F * I * 2);
    bf16* fcw_bf  = (bf16*)alloc((size_t)H * I * 2);
    bf16* ewih_bf = (bf16*)alloc((size_t)2 * G * H * 2);
    bf16* ewhh_bf = (bf16*)alloc((size_t)2 * G * H * 2);
    bf16* dwih_bf = (bf16*)alloc((size_t)2 * G * H * 2);
    bf16* dwhh_bf = (bf16*)alloc((size_t)2 * G * H * 2);
    bf16* xt_bf   = (bf16*)alloc((size_t)B * S * H * 2);
    bf16* hbf     = (bf16*)alloc((size_t)2 * 2 * B * H * 2);  // [L][slot][B*H]
    float* hf     = (float*)alloc((size_t)2 * B * H * 4);
    float* cf     = (float*)alloc((size_t)2 * B * H * 4);
    unsigned* flags = (unsigned*)alloc(128 * sizeof(unsigned)); // 2 phases x 64 WG flags

    size_t xp32_bytes = (size_t)B * S * G * 4;
    bool xp32 = (ws_size - off) >= xp32_bytes + 4096;
    float* Xf = nullptr; bf16* Xb = nullptr;
    if (xp32) Xf = (float*)alloc(xp32_bytes);
    else      Xb = (bf16*)alloc((size_t)B * S * G * 2);

    auto cvt = [&](const float* s, bf16* d, int n) {
        int blocks = (n / 4 + 255) / 256;
        if (blocks > 4096) blocks = 4096;
        f2b_kernel<<<blocks, 256, 0, stream>>>(s, d, n);
    };
    cvt(x, x_bf, B * S * I);
    cvt(fut, fut_bf, B * F * I);
    cvt(fc_w, fcw_bf, H * I);
    cvt(ewih, ewih_bf, 2 * G * H);
    cvt(ewhh, ewhh_bf, 2 * G * H);
    cvt(dwih, dwih_bf, 2 * G * H);
    cvt(dwhh, dwhh_bf, 2 * G * H);

    init_state_kernel<<<128, 256, 0, stream>>>(eh, ec, hf, cf, hbf, flags);

    auto gemm = [&](const bf16* A, const bf16* W, const float* bias,
                    float* Cf_, bf16* Cb_, int M, int N, int K) {
        gemm_bt<<<dim3(N / 64, M / 64), 256, 0, stream>>>(A, W, bias, Cf_, Cb_, M, N, K);
    };

    // FC: xt = bf16(x @ fc_w^T + fc_b)
    gemm(x_bf, fcw_bf, fc_b, nullptr, xt_bf, B * S, H, I);

    // ---- Encoder: xp for layer 0 only, then pipelined 2-layer persist ----
    gemm(xt_bf, ewih_bf, nullptr, Xf, Xb, B * S, G, H);
    lstm2_persist<<<64, 256, 0, stream>>>(
        S,
        hbf + 0 * 16384, hbf + 1 * 16384,    // layer0 ping-pong
        hbf + 2 * 16384, hbf + 3 * 16384,    // layer1 ping-pong
        hf, cf,
        ewhh_bf,                              // Whh0
        ewih_bf + (size_t)G * H,              // Wih1
        ewhh_bf + (size_t)G * H,              // Whh1
        Xf, Xb,
        ebih, ebhh, ebih + G, ebhh + G,
        nullptr, 0,
        flags + 0);

    // ---- Decoder: xp for layer 0 only, then pipelined 2-layer persist ----
    gemm(fut_bf, dwih_bf, nullptr, Xf, Xb, B * F, G, H);
    lstm2_persist<<<64, 256, 0, stream>>>(
        F,
        hbf + 0 * 16384, hbf + 1 * 16384,
        hbf + 2 * 16384, hbf + 3 * 16384,
        hf, cf,
        dwhh_bf,
        dwih_bf + (size_t)G * H,
        dwhh_bf + (size_t)G * H,
        Xf, Xb,
        dbih, dbhh, dbih + G, dbhh + G,
        out, (long)F * H,                     // dec_out [B,F,H] fp32
        flags + 64);

    // ---- Final decoder states ----
    tail_kernel<<<128, 256, 0, stream>>>(hf, cf, out);
}